// Round 3
// baseline (1885.673 us; speedup 1.0000x reference)
//
#include <hip/hip_runtime.h>
#include <hip/hip_bf16.h>

#define P_ 50000
#define NL_ 2000
#define NQ_ 6000
#define L_ 8
#define P2L_ 128
#define P2Q_ 64
#define D_ 32
#define ITERS_ 8

typedef __hip_bfloat16 bf16;
typedef unsigned short u16;

__device__ __forceinline__ float bfb2f(u16 u) {
    union { unsigned int i; float f; } c; c.i = ((unsigned int)u) << 16; return c.f;
}
__device__ __forceinline__ u16 f2bfb(float f) {
    union { bf16 h; u16 u; } c; c.h = __float2bfloat16(f); return c.u;
}

__device__ __forceinline__ float tanh_fast(float x) {
    // exact identity tanh(x) = 1 - 2/(e^{2x}+1); safe at both saturations
    return 1.f - 2.f / (__expf(2.f * x) + 1.f);
}

// Runtime dtype probe: read up to 64 leading elements as bf16. Legit bf16 data
// (traffic<=3012, capacity<=6e4, glorot weights, normals, zeros) is always in
// [1e-8,1e6] or exactly 0 and finite. f32 data misread as bf16 puts random
// mantissa bits into the exponent field of even-index elements -> insane
// values w.p. ~0.8 over 32 even samples => detection error ~1e-24.
__device__ bool detect_f32(const void* p, int n) {
    const u16* u = (const u16*)p;
    int m = n < 64 ? n : 64;
    bool bad = false;
    for (int k = 0; k < m; k++) {
        float v = bfb2f(u[k]);
        float av = fabsf(v);
        bool sane = (v == v) && (av <= 1e6f) && (av == 0.0f || av >= 1e-8f);
        bad |= !sane;
    }
    return bad;
}

// ---------------- input canonicalization: any-dtype -> f32 in ws -------------

struct CvtArgs { const void* p[40]; };

__global__ __launch_bounds__(256) void k_convert(CvtArgs a, float* __restrict__ dst) {
    static constexpr int N[40] = {
        50000,50000,50000,50000,50000,50000,50000,50000,50000,50000,
        2000,6000,6000,
        544,32,1024,32, 160,32,1024,32, 160,32,1024,32,
        2048,1024,32, 1024,1024,32, 1024,1024,32,
        512,16,256,16,16,1};
    int b = blockIdx.x, t = 0, off = 0;
    for (;;) {
        int nb = (N[t] + 255) >> 8;
        if (b < nb) break;
        b -= nb; off += N[t]; ++t;
    }
    const void* src = a.p[t];
    const int n = N[t];
    const bool isf = detect_f32(src, n);
    const int i = b * 256 + threadIdx.x;
    if (i < n)
        dst[off + i] = isf ? ((const float*)src)[i] : bfb2f(((const u16*)src)[i]);
}

// ---------------- embeddings (thread per entity, fully unrolled MLPs) --------

__global__ __launch_bounds__(256) void k_path_embed(
    const float* __restrict__ traffic, const float* __restrict__ packets,
    const float* __restrict__ eq_lambda, const float* __restrict__ avg_pkts_lambda,
    const float* __restrict__ exp_max_factor, const float* __restrict__ pkts_lambda_on,
    const float* __restrict__ avg_t_off, const float* __restrict__ avg_t_on,
    const float* __restrict__ ar_a, const float* __restrict__ sigma,
    const int* __restrict__ model,
    const float* __restrict__ w1, const float* __restrict__ b1,
    const float* __restrict__ w2, const float* __restrict__ b2,
    float* __restrict__ path_state)
{
    int p = blockIdx.x * 256 + threadIdx.x;
    if (p >= P_) return;
    float f[10];
    f[0] = (traffic[p]        - 1385.4059f) * (1.f / 859.8119f);
    f[1] = (packets[p]        - 1.4015f)    * (1.f / 0.8933f);
    f[2] = (eq_lambda[p]      - 1350.9712f) * (1.f / 858.3162f);
    f[3] = (avg_pkts_lambda[p]- 0.9117f)    * (1.f / 0.9724f);
    f[4] = (exp_max_factor[p] - 6.6636f)    * (1.f / 4.7151f);
    f[5] = (pkts_lambda_on[p] - 0.9116f)    * (1.f / 1.6513f);
    f[6] = (avg_t_off[p]      - 1.6649f)    * (1.f / 2.3564f);
    f[7] = (avg_t_on[p]       - 1.6649f)    * (1.f / 2.3564f);
    f[8] = ar_a[p];
    f[9] = sigma[p];
    int mrow = 2 + model[p];
    float h1[32];
#pragma unroll
    for (int d = 0; d < 32; d++) {
        float a = b1[d] + w1[mrow * 32 + d];
        a += f[0] * w1[0 * 32 + d];
        a += f[1] * w1[1 * 32 + d];
#pragma unroll
        for (int j = 0; j < 8; j++) a += f[2 + j] * w1[(9 + j) * 32 + d];
        h1[d] = fmaxf(a, 0.f);
    }
#pragma unroll
    for (int d = 0; d < 32; d++) {
        float a = b2[d];
#pragma unroll
        for (int k = 0; k < 32; k++) a += h1[k] * w2[k * 32 + d];
        path_state[p * 32 + d] = fmaxf(a, 0.f);
    }
}

__global__ __launch_bounds__(256) void k_queue_embed(
    const float* __restrict__ queue_size, const float* __restrict__ weight,
    const int* __restrict__ priority,
    const float* __restrict__ w1, const float* __restrict__ b1,
    const float* __restrict__ w2, const float* __restrict__ b2,
    float* __restrict__ queue_state)
{
    int q = blockIdx.x * 256 + threadIdx.x;
    if (q >= NQ_) return;
    float f0 = (queue_size[q] - 30259.1055f) * (1.f / 21410.0957f);
    float f4 = weight[q];
    int prow = 1 + priority[q];
    float h1[32];
#pragma unroll
    for (int d = 0; d < 32; d++) {
        float a = b1[d] + w1[prow * 32 + d]
                + f0 * w1[0 * 32 + d] + f4 * w1[4 * 32 + d];
        h1[d] = fmaxf(a, 0.f);
    }
#pragma unroll
    for (int d = 0; d < 32; d++) {
        float a = b2[d];
#pragma unroll
        for (int k = 0; k < 32; k++) a += h1[k] * w2[k * 32 + d];
        queue_state[q * 32 + d] = fmaxf(a, 0.f);
    }
}

__global__ __launch_bounds__(256) void k_link_embed(
    const float* __restrict__ traffic, const float* __restrict__ capacity,
    const int* __restrict__ policy,
    const int* __restrict__ p2l, const int* __restrict__ p2l_deg,
    const float* __restrict__ w1, const float* __restrict__ b1,
    const float* __restrict__ w2, const float* __restrict__ b2,
    float* __restrict__ link_state)
{
    int l = blockIdx.x * 256 + threadIdx.x;
    if (l >= NL_) return;
    int deg = p2l_deg[l];
    float s = 0.f;
    for (int j = 0; j < deg; j++) s += traffic[p2l[l * 2 * P2L_ + 2 * j]];
    float load = s / capacity[l];
    int prow = 1 + policy[l];
    float h1[32];
#pragma unroll
    for (int d = 0; d < 32; d++) {
        float a = b1[d] + w1[prow * 32 + d] + load * w1[0 * 32 + d];
        h1[d] = fmaxf(a, 0.f);
    }
#pragma unroll
    for (int d = 0; d < 32; d++) {
        float a = b2[d];
#pragma unroll
        for (int k = 0; k < 32; k++) a += h1[k] * w2[k * 32 + d];
        link_state[l * 32 + d] = fmaxf(a, 0.f);
    }
}

// ---------------- path RNN: 8 lanes/path, lane owns 4 dims -------------------
// pss layout: [path][slot 0..7][dim] bf16; slot t = h after scan step t+1
// (reference pss[:,0] is never gathered: pos >= 1, readout uses pss[:,1:]).

__global__ __launch_bounds__(256) void k_path_rnn(
    const int* __restrict__ q2p, const int* __restrict__ l2p,
    const int* __restrict__ length,
    const float* __restrict__ prW, const float* __restrict__ prU,
    const float* __restrict__ prB,
    const float* __restrict__ queue_state, const float* __restrict__ link_state,
    float* __restrict__ path_state, u16* __restrict__ pss)
{
    __shared__ float wl[97 * 32];      // rows 0..63 prW, 64..95 prU, row 96 = prB
    __shared__ float xs[32][100];      // stride 100 % 32 == 4 -> conflict-free
    const int tid = threadIdx.x;
    for (int idx = tid; idx < 64 * 32; idx += 256) wl[idx] = prW[idx];
    for (int idx = tid; idx < 32 * 32; idx += 256) wl[64 * 32 + idx] = prU[idx];
    if (tid < 32) wl[96 * 32 + tid] = prB[tid];
    __syncthreads();

    const int grp = tid >> 3;          // path slot in block (0..31)
    const int i   = tid & 7;           // dim group: dims 4i..4i+3
    const int path = blockIdx.x * 32 + grp;
    if (path >= P_) return;
    const int len = length[path];

    float4 h = *(const float4*)(path_state + (size_t)path * 32 + 4 * i);

#pragma unroll 1
    for (int t = 0; t < 8; t++) {
        const int q = q2p[path * 8 + t];
        const int l = l2p[path * 8 + t];
        const float4 qg = *(const float4*)(queue_state + (size_t)q * 32 + 4 * i);
        const float4 lg = *(const float4*)(link_state  + (size_t)l * 32 + 4 * i);
        *(float4*)&xs[grp][4 * i]      = qg;
        *(float4*)&xs[grp][32 + 4 * i] = lg;
        *(float4*)&xs[grp][64 + 4 * i] = h;

        float4 acc = *(const float4*)&wl[96 * 32 + 4 * i];  // prB
#pragma unroll
        for (int k = 0; k < 96; k += 4) {
            const float4 xv  = *(const float4*)&xs[grp][k];
            const float4 w0  = *(const float4*)&wl[(k + 0) * 32 + 4 * i];
            const float4 w1v = *(const float4*)&wl[(k + 1) * 32 + 4 * i];
            const float4 w2v = *(const float4*)&wl[(k + 2) * 32 + 4 * i];
            const float4 w3v = *(const float4*)&wl[(k + 3) * 32 + 4 * i];
            acc.x += xv.x * w0.x + xv.y * w1v.x + xv.z * w2v.x + xv.w * w3v.x;
            acc.y += xv.x * w0.y + xv.y * w1v.y + xv.z * w2v.y + xv.w * w3v.y;
            acc.z += xv.x * w0.z + xv.y * w1v.z + xv.z * w2v.z + xv.w * w3v.z;
            acc.w += xv.x * w0.w + xv.y * w1v.w + xv.z * w2v.w + xv.w * w3v.w;
        }
        const bool m = (t < len);
        h.x = m ? tanh_fast(acc.x) : h.x;
        h.y = m ? tanh_fast(acc.y) : h.y;
        h.z = m ? tanh_fast(acc.z) : h.z;
        h.w = m ? tanh_fast(acc.w) : h.w;
        union { ushort4 v; u16 s[4]; } pk;
        pk.s[0] = f2bfb(h.x); pk.s[1] = f2bfb(h.y);
        pk.s[2] = f2bfb(h.z); pk.s[3] = f2bfb(h.w);
        *(ushort4*)(pss + (size_t)path * 256 + t * 32 + 4 * i) = pk.v;
    }
    *(float4*)(path_state + (size_t)path * 32 + 4 * i) = h;
}

// ---------------- queue update ----------------------------------------------

__global__ __launch_bounds__(256) void k_queue_update(
    const int* __restrict__ p2q, const int* __restrict__ p2q_deg,
    const float* __restrict__ qrW, const float* __restrict__ qrU,
    const float* __restrict__ qrB,
    const u16* __restrict__ pss, float* __restrict__ queue_state)
{
    __shared__ float wl[65 * 32];      // rows 0..31 qrW, 32..63 qrU, 64 = qrB
    __shared__ float xs[32][68];
    const int tid = threadIdx.x;
    for (int idx = tid; idx < 32 * 32; idx += 256) {
        wl[idx]           = qrW[idx];
        wl[32 * 32 + idx] = qrU[idx];
    }
    if (tid < 32) wl[64 * 32 + tid] = qrB[tid];
    __syncthreads();

    const int grp = tid >> 3, i = tid & 7;
    const int q = blockIdx.x * 32 + grp;
    if (q >= NQ_) return;
    const int deg = p2q_deg[q];
    float4 ps = {0.f, 0.f, 0.f, 0.f};
#pragma unroll 4
    for (int j = 0; j < deg; j++) {
        const int pj  = p2q[q * 2 * P2Q_ + 2 * j];
        int pos = p2q[q * 2 * P2Q_ + 2 * j + 1];
        int s = pos - 1; s = s < 0 ? 0 : (s > 7 ? 7 : s);
        const ushort4 v = *(const ushort4*)(pss + (size_t)pj * 256 + s * 32 + 4 * i);
        ps.x += bfb2f(v.x); ps.y += bfb2f(v.y);
        ps.z += bfb2f(v.z); ps.w += bfb2f(v.w);
    }
    const float4 qs = *(const float4*)(queue_state + (size_t)q * 32 + 4 * i);
    *(float4*)&xs[grp][4 * i]      = ps;
    *(float4*)&xs[grp][32 + 4 * i] = qs;

    float4 acc = *(const float4*)&wl[64 * 32 + 4 * i];
#pragma unroll
    for (int k = 0; k < 64; k += 4) {
        const float4 xv  = *(const float4*)&xs[grp][k];
        const float4 w0  = *(const float4*)&wl[(k + 0) * 32 + 4 * i];
        const float4 w1v = *(const float4*)&wl[(k + 1) * 32 + 4 * i];
        const float4 w2v = *(const float4*)&wl[(k + 2) * 32 + 4 * i];
        const float4 w3v = *(const float4*)&wl[(k + 3) * 32 + 4 * i];
        acc.x += xv.x * w0.x + xv.y * w1v.x + xv.z * w2v.x + xv.w * w3v.x;
        acc.y += xv.x * w0.y + xv.y * w1v.y + xv.z * w2v.y + xv.w * w3v.y;
        acc.z += xv.x * w0.z + xv.y * w1v.z + xv.z * w2v.z + xv.w * w3v.z;
        acc.w += xv.x * w0.w + xv.y * w1v.w + xv.z * w2v.w + xv.w * w3v.w;
    }
    float4 nh;
    nh.x = tanh_fast(acc.x); nh.y = tanh_fast(acc.y);
    nh.z = tanh_fast(acc.z); nh.w = tanh_fast(acc.w);
    *(float4*)(queue_state + (size_t)q * 32 + 4 * i) = nh;
}

// ---------------- link update ------------------------------------------------

__global__ __launch_bounds__(256) void k_link_update(
    const int* __restrict__ q2l,
    const float* __restrict__ lrW, const float* __restrict__ lrU,
    const float* __restrict__ lrB,
    const float* __restrict__ queue_state, float* __restrict__ link_state)
{
    __shared__ float wl[65 * 32];      // rows 0..31 lrW, 32..63 lrU, 64 = lrB
    __shared__ float xs[32][68];
    const int tid = threadIdx.x;
    for (int idx = tid; idx < 32 * 32; idx += 256) {
        wl[idx]           = lrW[idx];
        wl[32 * 32 + idx] = lrU[idx];
    }
    if (tid < 32) wl[64 * 32 + tid] = lrB[tid];
    __syncthreads();

    const int grp = tid >> 3, i = tid & 7;
    const int l = blockIdx.x * 32 + grp;
    if (l >= NL_) return;
    float4 h = *(const float4*)(link_state + (size_t)l * 32 + 4 * i);
#pragma unroll 1
    for (int t = 0; t < 3; t++) {
        const int qq = q2l[l * 3 + t];
        const float4 qg = *(const float4*)(queue_state + (size_t)qq * 32 + 4 * i);
        *(float4*)&xs[grp][4 * i]      = qg;
        *(float4*)&xs[grp][32 + 4 * i] = h;
        float4 acc = *(const float4*)&wl[64 * 32 + 4 * i];
#pragma unroll
        for (int k = 0; k < 64; k += 4) {
            const float4 xv  = *(const float4*)&xs[grp][k];
            const float4 w0  = *(const float4*)&wl[(k + 0) * 32 + 4 * i];
            const float4 w1v = *(const float4*)&wl[(k + 1) * 32 + 4 * i];
            const float4 w2v = *(const float4*)&wl[(k + 2) * 32 + 4 * i];
            const float4 w3v = *(const float4*)&wl[(k + 3) * 32 + 4 * i];
            acc.x += xv.x * w0.x + xv.y * w1v.x + xv.z * w2v.x + xv.w * w3v.x;
            acc.y += xv.x * w0.y + xv.y * w1v.y + xv.z * w2v.y + xv.w * w3v.y;
            acc.z += xv.x * w0.z + xv.y * w1v.z + xv.z * w2v.z + xv.w * w3v.z;
            acc.w += xv.x * w0.w + xv.y * w1v.w + xv.z * w2v.w + xv.w * w3v.w;
        }
        h.x = tanh_fast(acc.x); h.y = tanh_fast(acc.y);
        h.z = tanh_fast(acc.z); h.w = tanh_fast(acc.w);
    }
    *(float4*)(link_state + (size_t)l * 32 + 4 * i) = h;
}

// ---------------- readout: 8 lanes/path, lane owns 2 of 16 dims --------------

__global__ __launch_bounds__(256) void k_readout(
    const void* __restrict__ raw_traffic,
    const float* __restrict__ traffic, const float* __restrict__ packets,
    const float* __restrict__ capacity,
    const int* __restrict__ l2p, const int* __restrict__ length,
    const float* __restrict__ w1, const float* __restrict__ b1,
    const float* __restrict__ w2, const float* __restrict__ b2,
    const float* __restrict__ w3, const float* __restrict__ b3,
    const u16* __restrict__ pss, void* __restrict__ out)
{
    __shared__ float wl[817];   // w1[512] b1@512 w2@528 b2@784 w3@800 b3@816
    __shared__ float xs[32][52];
    const int tid = threadIdx.x;
    for (int idx = tid; idx < 512; idx += 256) wl[idx] = w1[idx];
    if (tid < 256) wl[528 + tid] = w2[tid];
    if (tid < 16) {
        wl[512 + tid] = b1[tid];
        wl[784 + tid] = b2[tid];
        wl[800 + tid] = w3[tid];
    }
    if (tid == 0) wl[816] = b3[0];
    __syncthreads();

    const int grp = tid >> 3, i = tid & 7;
    const int p = blockIdx.x * 32 + grp;
    if (p >= P_) return;
    const bool outf32 = detect_f32(raw_traffic, P_);   // output dtype follows inputs
    const int len = length[p];
    float qd = 0.f, ts = 0.f;
#pragma unroll 1
    for (int t = 0; t < 8; t++) {
        const ushort4 hu = *(const ushort4*)(pss + (size_t)p * 256 + t * 32 + 4 * i);
        float4 hv;
        hv.x = bfb2f(hu.x); hv.y = bfb2f(hu.y); hv.z = bfb2f(hu.z); hv.w = bfb2f(hu.w);
        *(float4*)&xs[grp][4 * i] = hv;
        float a0 = wl[512 + 2 * i], a1 = wl[512 + 2 * i + 1];
#pragma unroll
        for (int k = 0; k < 32; k += 4) {
            const float4 xv = *(const float4*)&xs[grp][k];
            const float2 u0 = *(const float2*)&wl[(k + 0) * 16 + 2 * i];
            const float2 u1 = *(const float2*)&wl[(k + 1) * 16 + 2 * i];
            const float2 u2 = *(const float2*)&wl[(k + 2) * 16 + 2 * i];
            const float2 u3 = *(const float2*)&wl[(k + 3) * 16 + 2 * i];
            a0 += xv.x * u0.x + xv.y * u1.x + xv.z * u2.x + xv.w * u3.x;
            a1 += xv.x * u0.y + xv.y * u1.y + xv.z * u2.y + xv.w * u3.y;
        }
        a0 = fmaxf(a0, 0.f); a1 = fmaxf(a1, 0.f);
        *(float2*)&xs[grp][32 + 2 * i] = make_float2(a0, a1);
        float c0 = wl[784 + 2 * i], c1 = wl[784 + 2 * i + 1];
#pragma unroll
        for (int k = 0; k < 16; k += 4) {
            const float4 xv = *(const float4*)&xs[grp][32 + k];
            const float2 u0 = *(const float2*)&wl[528 + (k + 0) * 16 + 2 * i];
            const float2 u1 = *(const float2*)&wl[528 + (k + 1) * 16 + 2 * i];
            const float2 u2 = *(const float2*)&wl[528 + (k + 2) * 16 + 2 * i];
            const float2 u3 = *(const float2*)&wl[528 + (k + 3) * 16 + 2 * i];
            c0 += xv.x * u0.x + xv.y * u1.x + xv.z * u2.x + xv.w * u3.x;
            c1 += xv.x * u0.y + xv.y * u1.y + xv.z * u2.y + xv.w * u3.y;
        }
        c0 = fmaxf(c0, 0.f); c1 = fmaxf(c1, 0.f);
        float pv = c0 * wl[800 + 2 * i] + c1 * wl[800 + 2 * i + 1];
        pv += __shfl_xor(pv, 1, 8);
        pv += __shfl_xor(pv, 2, 8);
        pv += __shfl_xor(pv, 4, 8);
        const float occv = pv + wl[816];
        if (t < len) {
            const float inv = 1.f / capacity[l2p[p * 8 + t]];
            qd += occv * inv;
            ts += inv;
        }
    }
    if (i == 0) {
        const float res = qd + (traffic[p] / packets[p]) * ts;
        if (outf32) ((float*)out)[p] = res;
        else        ((bf16*)out)[p] = __float2bfloat16(res);
    }
}

// ---------------- launcher ---------------------------------------------------

extern "C" void kernel_launch(void* const* d_in, const int* in_sizes, int n_in,
                              void* d_out, int out_size, void* d_ws, size_t ws_size,
                              hipStream_t stream)
{
    static const int CVT_N[40] = {
        50000,50000,50000,50000,50000,50000,50000,50000,50000,50000,
        2000,6000,6000,
        544,32,1024,32, 160,32,1024,32, 160,32,1024,32,
        2048,1024,32, 1024,1024,32, 1024,1024,32,
        512,16,256,16,16,1};

    const int*  length   = (const int*)d_in[13];
    const int*  model    = (const int*)d_in[14];
    const int*  policy   = (const int*)d_in[15];
    const int*  priority = (const int*)d_in[16];
    const int*  q2p      = (const int*)d_in[17];
    const int*  l2p      = (const int*)d_in[18];
    const int*  p2l      = (const int*)d_in[19];
    const int*  p2l_deg  = (const int*)d_in[20];
    const int*  p2q      = (const int*)d_in[21];
    const int*  p2q_deg  = (const int*)d_in[22];
    const int*  q2l      = (const int*)d_in[23];

    // float-tensor table: d_in[0..12] data, d_in[24..50] weights
    CvtArgs ca;
    for (int i = 0; i < 13; i++) ca.p[i] = d_in[i];
    for (int i = 0; i < 27; i++) ca.p[13 + i] = d_in[24 + i];

    int off[41]; off[0] = 0;
    for (int i = 0; i < 40; i++) off[i + 1] = off[i] + CVT_N[i];
    int nblk = 0;
    for (int i = 0; i < 40; i++) nblk += (CVT_N[i] + 255) / 256;

    float* ws = (float*)d_ws;
    const float* c_traffic    = ws + off[0];
    const float* c_packets    = ws + off[1];
    const float* c_eq_lambda  = ws + off[2];
    const float* c_apl        = ws + off[3];
    const float* c_emf        = ws + off[4];
    const float* c_plo        = ws + off[5];
    const float* c_atoff      = ws + off[6];
    const float* c_aton       = ws + off[7];
    const float* c_ar_a       = ws + off[8];
    const float* c_sigma      = ws + off[9];
    const float* c_capacity   = ws + off[10];
    const float* c_queue_size = ws + off[11];
    const float* c_weight     = ws + off[12];
    const float* c_pe_w1 = ws + off[13]; const float* c_pe_b1 = ws + off[14];
    const float* c_pe_w2 = ws + off[15]; const float* c_pe_b2 = ws + off[16];
    const float* c_le_w1 = ws + off[17]; const float* c_le_b1 = ws + off[18];
    const float* c_le_w2 = ws + off[19]; const float* c_le_b2 = ws + off[20];
    const float* c_qe_w1 = ws + off[21]; const float* c_qe_b1 = ws + off[22];
    const float* c_qe_w2 = ws + off[23]; const float* c_qe_b2 = ws + off[24];
    const float* c_prW = ws + off[25]; const float* c_prU = ws + off[26];
    const float* c_prB = ws + off[27];
    const float* c_qrW = ws + off[28]; const float* c_qrU = ws + off[29];
    const float* c_qrB = ws + off[30];
    const float* c_lrW = ws + off[31]; const float* c_lrU = ws + off[32];
    const float* c_lrB = ws + off[33];
    const float* c_ro_w1 = ws + off[34]; const float* c_ro_b1 = ws + off[35];
    const float* c_ro_w2 = ws + off[36]; const float* c_ro_b2 = ws + off[37];
    const float* c_ro_w3 = ws + off[38]; const float* c_ro_b3 = ws + off[39];

    size_t base = ((size_t)off[40] + 63) & ~(size_t)63;     // 526272 floats
    float* path_state  = ws + base;                          // P*32
    float* queue_state = path_state + (size_t)P_ * 32;       // NQ*32
    float* link_state  = queue_state + (size_t)NQ_ * 32;     // NL*32
    u16*   pss         = (u16*)(link_state + (size_t)NL_ * 32); // P*256 bf16
    // total ws: ~9.53 MB (f32 region) + 25.6 MB (pss) = 35.1 MB

    k_convert<<<nblk, 256, 0, stream>>>(ca, ws);

    k_path_embed<<<(P_ + 255) / 256, 256, 0, stream>>>(
        c_traffic, c_packets, c_eq_lambda, c_apl, c_emf, c_plo, c_atoff, c_aton,
        c_ar_a, c_sigma, model, c_pe_w1, c_pe_b1, c_pe_w2, c_pe_b2, path_state);
    k_queue_embed<<<(NQ_ + 255) / 256, 256, 0, stream>>>(
        c_queue_size, c_weight, priority, c_qe_w1, c_qe_b1, c_qe_w2, c_qe_b2,
        queue_state);
    k_link_embed<<<(NL_ + 255) / 256, 256, 0, stream>>>(
        c_traffic, c_capacity, policy, p2l, p2l_deg,
        c_le_w1, c_le_b1, c_le_w2, c_le_b2, link_state);

    for (int it = 0; it < ITERS_; ++it) {
        k_path_rnn<<<(P_ + 31) / 32, 256, 0, stream>>>(
            q2p, l2p, length, c_prW, c_prU, c_prB, queue_state, link_state,
            path_state, pss);
        k_queue_update<<<(NQ_ + 31) / 32, 256, 0, stream>>>(
            p2q, p2q_deg, c_qrW, c_qrU, c_qrB, pss, queue_state);
        k_link_update<<<(NL_ + 31) / 32, 256, 0, stream>>>(
            q2l, c_lrW, c_lrU, c_lrB, queue_state, link_state);
    }

    k_readout<<<(P_ + 31) / 32, 256, 0, stream>>>(
        d_in[0], c_traffic, c_packets, c_capacity, l2p, length,
        c_ro_w1, c_ro_b1, c_ro_w2, c_ro_b2, c_ro_w3, c_ro_b3, pss, d_out);
}